// Round 7
// baseline (73.062 us; speedup 1.0000x reference)
//
#include <hip/hip_runtime.h>

#define BN 512
#define DIM 128
#define TMARGIN 0.3f
#define NT 1024
#define NW 16     // waves per block
#define NBLK 256  // 2 anchors per block, 1 block/CU
#define BIGF 1e30f

#define FMA4(ACC, U, V)                                                \
    ACC.x += U.x * V.x; ACC.y += U.y * V.y;                            \
    ACC.z += U.z * V.z; ACC.w += U.w * V.w;

__device__ __forceinline__ float hsum4(float4 v) {
    return (v.x + v.y) + (v.z + v.w);
}

// ---------------------------------------------------------------------------
// SINGLE dispatch, round-3 body (best measured: 63.9us) + TWO-LEVEL ticket.
//
// Round-4 calibration: 256 agent-scope fetch_adds on ONE line serialize
// cross-XCD (~55ns each ~= 14us) -> lost. Fix is fanout: 32 leaf counters
// (8 blocks each, parallel across lines, ~0.4us) + 1 root counter touched
// by only 32 time-spread group leaders (<2us). No spinning -> no
// co-residency assumption, no deadlock (no block ever waits).
//
// Ticket + partials live in MODULE globals: immune to the harness's
// per-iteration workspace re-poison; zero at module load; the finisher
// resets them before kernel end, and stream ordering serializes graph
// replays, so each replay starts from zero.
//
// Finisher reduction = EXACT order of the old finalize kernel (lane-stride
// + shfl_xor tree) -> bit-identical output.
//
// Retained (measured wins): NT=1024 / 4 waves/SIMD; anchors in registers
// (kl-slice); negative mask folded into drow (1e30 sentinel, no labels in
// Phase B); positive DISTANCES compacted inline in Phase A.
// ---------------------------------------------------------------------------
__device__ float g_psum[NBLK];
__device__ float g_pcnt[NBLK];
__device__ int   g_leaf[32];   // 8 blocks per leaf
__device__ int   g_root = 0;   // 32 leaders

__global__ __launch_bounds__(NT, 4) void triplet_fused_kernel(
        const float* __restrict__ emb,
        const int* __restrict__ labels,
        float* __restrict__ out) {   // [1]
    const int ia   = blockIdx.x;         // anchor A
    const int ib   = blockIdx.x + NBLK;  // anchor B
    const int tid  = threadIdx.x;
    const int lane = tid & 63;
    const int wave = tid >> 6;
    const int rl   = lane >> 2;   // row-in-group 0..15
    const int kl   = lane & 3;    // k-lane 0..3

    __shared__ float drowA[BN], drowB[BN];   // negatives-only distance rows
    __shared__ float pdA[BN], pdB[BN];       // positive distances (compact)
    __shared__ int   nposA, nposB;
    __shared__ float wsum[NW];
    __shared__ int   wcnt[NW];
    __shared__ int   sfin;

    const float4* emb4 = (const float4*)emb;
    const int liA = labels[ia];
    const int liB = labels[ib];

    // --- anchor fragments in registers (kl-slice only) --------------------
    float4 ra[8], rb[8];
#pragma unroll
    for (int q = 0; q < 8; ++q) {
        ra[q] = emb4[(size_t)ia * 32 + kl + 4 * q];
        rb[q] = emb4[(size_t)ib * 32 + kl + 4 * q];
    }
    // squared norms: per-thread partial over the kl-slice, then 4-lane sum
    float4 sa = {0,0,0,0}, sb = {0,0,0,0};
#pragma unroll
    for (int q = 0; q < 8; ++q) { FMA4(sa, ra[q], ra[q]); FMA4(sb, rb[q], rb[q]); }
    float sqA = hsum4(sa), sqB = hsum4(sb);
    sqA += __shfl_xor(sqA, 1); sqA += __shfl_xor(sqA, 2);
    sqB += __shfl_xor(sqB, 1); sqB += __shfl_xor(sqB, 2);

    if (tid == 0) { nposA = 0; nposB = 0; }
    __syncthreads();

    // ---------------- Phase A: both dist rows, one pass over emb ----------
    // 16 waves x 16 rows/iter; 4 lanes per row, 64 B contiguous per group.
#pragma unroll
    for (int c = 0; c < 2; ++c) {
        const int r = c * 256 + wave * 16 + rl;
        float4 da = {0,0,0,0}, db = {0,0,0,0}, qq = {0,0,0,0};
#pragma unroll
        for (int q = 0; q < 8; ++q) {
            const float4 v = emb4[(size_t)r * 32 + kl + 4 * q];
            FMA4(da, ra[q], v);
            FMA4(db, rb[q], v);
            FMA4(qq, v, v);
        }
        float dotA = hsum4(da), dotB = hsum4(db), sqj = hsum4(qq);
        dotA += __shfl_down(dotA, 1); dotA += __shfl_down(dotA, 2);
        dotB += __shfl_down(dotB, 1); dotB += __shfl_down(dotB, 2);
        sqj  += __shfl_down(sqj, 1);  sqj  += __shfl_down(sqj, 2);
        if (kl == 0) {
            const int   lr = labels[r];
            const float dA = sqrtf(fmaxf(sqA + sqj - 2.f * dotA, 1e-12f));
            const float dB = sqrtf(fmaxf(sqB + sqj - 2.f * dotB, 1e-12f));
            const bool  eqA = (lr == liA), eqB = (lr == liB);
            drowA[r] = eqA ? BIGF : dA;     // self has eqA -> excluded too
            drowB[r] = eqB ? BIGF : dB;
            if (eqA && r != ia) { int p = atomicAdd(&nposA, 1); pdA[p] = dA; }
            if (eqB && r != ib) { int p = atomicAdd(&nposB, 1); pdB[p] = dB; }
        }
    }
    __syncthreads();

    // ---------------- Phase B: waves 0-7 anchor A, 8-15 anchor B ----------
    const int grp  = wave >> 3;             // 0: A, 1: B
    const int wsub = wave & 7;
    const float* drow = grp ? drowB : drowA;
    const float* pd   = grp ? pdB   : pdA;
    const int    npos = grp ? nposB : nposA;

    // min over negatives (BIGF is identity); has_neg == (mn < 1e29)
    float mn = BIGF;
#pragma unroll
    for (int kk = 0; kk < BN / 64; ++kk)
        mn = fminf(mn, drow[lane + 64 * kk]);
#pragma unroll
    for (int off = 32; off; off >>= 1)
        mn = fminf(mn, __shfl_xor(mn, off));

    float lsum = 0.f;
    int   lcnt = 0;
    if (mn < 1e29f) {
        for (int p = wsub; p < npos; p += 8) {
            const float dap = pd[p];
            const float hi  = dap + TMARGIN;
            float smax = -BIGF;
#pragma unroll
            for (int kk = 0; kk < BN / 64; ++kk) {
                const float dan = drow[lane + 64 * kk];
                if (dan > dap && dan < hi) smax = fmaxf(smax, dan);
            }
#pragma unroll
            for (int off = 32; off; off >>= 1)
                smax = fmaxf(smax, __shfl_xor(smax, off));
            const float dneg = (smax > -1e29f) ? smax : mn;
            lsum += fmaxf(dap - dneg + TMARGIN, 0.f);
            lcnt += 1;
        }
    }
    if (lane == 0) { wsum[wave] = lsum; wcnt[wave] = lcnt; }
    __syncthreads();

    // ---- publish partial (agent scope), two-level ticket ------------------
    if (tid == 0) {
        float s = 0.f;
        int   c = 0;
#pragma unroll
        for (int w = 0; w < NW; ++w) { s += wsum[w]; c += wcnt[w]; }
        __hip_atomic_store(&g_psum[blockIdx.x], s, __ATOMIC_RELEASE,
                           __HIP_MEMORY_SCOPE_AGENT);
        __hip_atomic_store(&g_pcnt[blockIdx.x], (float)c, __ATOMIC_RELEASE,
                           __HIP_MEMORY_SCOPE_AGENT);
        sfin = 0;
        const int l = __hip_atomic_fetch_add(&g_leaf[blockIdx.x >> 3], 1,
                                             __ATOMIC_ACQ_REL,
                                             __HIP_MEMORY_SCOPE_AGENT);
        if (l == 7) {   // last of this 8-block group
            const int rt = __hip_atomic_fetch_add(&g_root, 1,
                                                  __ATOMIC_ACQ_REL,
                                                  __HIP_MEMORY_SCOPE_AGENT);
            if (rt == 31) sfin = 1;   // last group leader -> finisher
        }
    }
    __syncthreads();

    // ---- finisher block: reduce 256 slots (same order as old finalize) ---
    if (sfin && wave == 0) {
        float s = 0.f, c = 0.f;
#pragma unroll
        for (int i = 0; i < NBLK / 64; ++i) {
            s += __hip_atomic_load(&g_psum[lane + 64 * i], __ATOMIC_ACQUIRE,
                                   __HIP_MEMORY_SCOPE_AGENT);
            c += __hip_atomic_load(&g_pcnt[lane + 64 * i], __ATOMIC_ACQUIRE,
                                   __HIP_MEMORY_SCOPE_AGENT);
        }
#pragma unroll
        for (int off = 32; off; off >>= 1) {
            s += __shfl_xor(s, off);
            c += __shfl_xor(c, off);
        }
        if (lane == 0)
            out[0] = (c > 0.f) ? (s / fmaxf(c, 1.f)) : 0.f;
        // reset counters for next graph replay (no other block is alive;
        // stream order serializes replays)
        if (lane < 32)
            __hip_atomic_store(&g_leaf[lane], 0, __ATOMIC_RELEASE,
                               __HIP_MEMORY_SCOPE_AGENT);
        if (lane == 0)
            __hip_atomic_store(&g_root, 0, __ATOMIC_RELEASE,
                               __HIP_MEMORY_SCOPE_AGENT);
    }
}

extern "C" void kernel_launch(void* const* d_in, const int* in_sizes, int n_in,
                              void* d_out, int out_size, void* d_ws, size_t ws_size,
                              hipStream_t stream) {
    const float* emb    = (const float*)d_in[0];
    const int*   labels = (const int*)d_in[1];
    float*       out    = (float*)d_out;
    (void)d_ws; (void)ws_size;   // workspace unused (state in module globals)

    triplet_fused_kernel<<<NBLK, NT, 0, stream>>>(emb, labels, out);
}

// Round 8
// 63.834 us; speedup vs baseline: 1.1446x; 1.1446x over previous
//
#include <hip/hip_runtime.h>

#define BN 512
#define DIM 128
#define TMARGIN 0.3f
#define NT 1024
#define NW 16     // waves per block
#define NBLK 256  // 2 anchors per block, 1 block/CU
#define BIGF 1e30f

#define FMA4(ACC, U, V)                                                \
    ACC.x += U.x * V.x; ACC.y += U.y * V.y;                            \
    ACC.z += U.z * V.z; ACC.w += U.w * V.w;

__device__ __forceinline__ float hsum4(float4 v) {
    return (v.x + v.y) + (v.z + v.w);
}

// ---------------------------------------------------------------------------
// FINAL: round-3 configuration verbatim — the measured optimum (63.9us).
//
// Structure ledger (7 rounds of A/B on this problem):
//  * two kernels (triplet + 1-wave finalize) BEATS every single-dispatch
//    variant: grid.sync +46us (r2), flat ticket +8.7us (r4), two-level
//    ticket +9.2us (r7). In-kernel grid consensus costs >=9us on MI355X
//    regardless of fanout; a graph-captured dependent dispatch costs ~5us.
//  * 256 blocks x 1024 thr x 2 anchors beats 4-anchor/128-block (+2us, r5)
//    and NT=512 (+2.3us, r3): latency-bound -> shortest per-block critical
//    path wins.
//  * Phase A load-merge was neutral (r6) — load-issue order isn't the
//    bottleneck; the body is at its latency floor on HBM-cold input (the
//    harness's 268MB per-iteration re-poison evicts emb from L2+L3).
// Floor accounting: 40.5us BW-bound workspace fill (in-stream, harness) +
// ~10-14us dispatch/graph overhead + ~10us kernel bodies ~= 64us measured.
//
// Body techniques (each A/B-verified): anchors in registers (kl-slice);
// negative mask folded into drow (1e30 sentinel -> no labels in Phase B);
// positive DISTANCES compacted inline in Phase A; 16 waves = 4 waves/SIMD.
// ---------------------------------------------------------------------------
__global__ __launch_bounds__(NT, 4) void triplet_fused_kernel(
        const float* __restrict__ emb,
        const int* __restrict__ labels,
        float* __restrict__ psum,    // [NBLK]
        float* __restrict__ pcnt) {  // [NBLK]
    const int ia   = blockIdx.x;         // anchor A
    const int ib   = blockIdx.x + NBLK;  // anchor B
    const int tid  = threadIdx.x;
    const int lane = tid & 63;
    const int wave = tid >> 6;
    const int rl   = lane >> 2;   // row-in-group 0..15
    const int kl   = lane & 3;    // k-lane 0..3

    __shared__ float drowA[BN], drowB[BN];   // negatives-only distance rows
    __shared__ float pdA[BN], pdB[BN];       // positive distances (compact)
    __shared__ int   nposA, nposB;
    __shared__ float wsum[NW];
    __shared__ int   wcnt[NW];

    const float4* emb4 = (const float4*)emb;
    const int liA = labels[ia];
    const int liB = labels[ib];

    // --- anchor fragments in registers (kl-slice only) --------------------
    float4 ra[8], rb[8];
#pragma unroll
    for (int q = 0; q < 8; ++q) {
        ra[q] = emb4[(size_t)ia * 32 + kl + 4 * q];
        rb[q] = emb4[(size_t)ib * 32 + kl + 4 * q];
    }
    // squared norms: per-thread partial over the kl-slice, then 4-lane sum
    float4 sa = {0,0,0,0}, sb = {0,0,0,0};
#pragma unroll
    for (int q = 0; q < 8; ++q) { FMA4(sa, ra[q], ra[q]); FMA4(sb, rb[q], rb[q]); }
    float sqA = hsum4(sa), sqB = hsum4(sb);
    sqA += __shfl_xor(sqA, 1); sqA += __shfl_xor(sqA, 2);
    sqB += __shfl_xor(sqB, 1); sqB += __shfl_xor(sqB, 2);

    if (tid == 0) { nposA = 0; nposB = 0; }
    __syncthreads();

    // ---------------- Phase A: both dist rows, one pass over emb ----------
    // 16 waves x 16 rows/iter; 4 lanes per row, 64 B contiguous per group.
#pragma unroll
    for (int c = 0; c < 2; ++c) {
        const int r = c * 256 + wave * 16 + rl;
        float4 da = {0,0,0,0}, db = {0,0,0,0}, qq = {0,0,0,0};
#pragma unroll
        for (int q = 0; q < 8; ++q) {
            const float4 v = emb4[(size_t)r * 32 + kl + 4 * q];
            FMA4(da, ra[q], v);
            FMA4(db, rb[q], v);
            FMA4(qq, v, v);
        }
        float dotA = hsum4(da), dotB = hsum4(db), sqj = hsum4(qq);
        dotA += __shfl_down(dotA, 1); dotA += __shfl_down(dotA, 2);
        dotB += __shfl_down(dotB, 1); dotB += __shfl_down(dotB, 2);
        sqj  += __shfl_down(sqj, 1);  sqj  += __shfl_down(sqj, 2);
        if (kl == 0) {
            const int   lr = labels[r];
            const float dA = sqrtf(fmaxf(sqA + sqj - 2.f * dotA, 1e-12f));
            const float dB = sqrtf(fmaxf(sqB + sqj - 2.f * dotB, 1e-12f));
            const bool  eqA = (lr == liA), eqB = (lr == liB);
            drowA[r] = eqA ? BIGF : dA;     // self has eqA -> excluded too
            drowB[r] = eqB ? BIGF : dB;
            if (eqA && r != ia) { int p = atomicAdd(&nposA, 1); pdA[p] = dA; }
            if (eqB && r != ib) { int p = atomicAdd(&nposB, 1); pdB[p] = dB; }
        }
    }
    __syncthreads();

    // ---------------- Phase B: waves 0-7 anchor A, 8-15 anchor B ----------
    const int grp  = wave >> 3;             // 0: A, 1: B
    const int wsub = wave & 7;
    const float* drow = grp ? drowB : drowA;
    const float* pd   = grp ? pdB   : pdA;
    const int    npos = grp ? nposB : nposA;

    // min over negatives (BIGF is identity); has_neg == (mn < 1e29)
    float mn = BIGF;
#pragma unroll
    for (int kk = 0; kk < BN / 64; ++kk)
        mn = fminf(mn, drow[lane + 64 * kk]);
#pragma unroll
    for (int off = 32; off; off >>= 1)
        mn = fminf(mn, __shfl_xor(mn, off));

    float lsum = 0.f;
    int   lcnt = 0;
    if (mn < 1e29f) {
        for (int p = wsub; p < npos; p += 8) {
            const float dap = pd[p];
            const float hi  = dap + TMARGIN;
            float smax = -BIGF;
#pragma unroll
            for (int kk = 0; kk < BN / 64; ++kk) {
                const float dan = drow[lane + 64 * kk];
                if (dan > dap && dan < hi) smax = fmaxf(smax, dan);
            }
#pragma unroll
            for (int off = 32; off; off >>= 1)
                smax = fmaxf(smax, __shfl_xor(smax, off));
            const float dneg = (smax > -1e29f) ? smax : mn;
            lsum += fmaxf(dap - dneg + TMARGIN, 0.f);
            lcnt += 1;
        }
    }
    if (lane == 0) { wsum[wave] = lsum; wcnt[wave] = lcnt; }
    __syncthreads();

    // one combined partial per block; plain stores (kernel-end flush)
    if (tid == 0) {
        float s = 0.f;
        int   c = 0;
#pragma unroll
        for (int w = 0; w < NW; ++w) { s += wsum[w]; c += wcnt[w]; }
        psum[blockIdx.x] = s;
        pcnt[blockIdx.x] = (float)c;
    }
}

// ---------------------------------------------------------------------------
// Finalize: one wave reduces the 256 partial slots. No LDS, no barriers.
// ---------------------------------------------------------------------------
__global__ __launch_bounds__(64) void finalize_kernel(
        const float* __restrict__ psum,
        const float* __restrict__ pcnt,
        float* __restrict__ out) {
    const int lane = threadIdx.x;
    float s = 0.f, c = 0.f;
#pragma unroll
    for (int i = 0; i < 4; ++i) {
        s += psum[lane + 64 * i];
        c += pcnt[lane + 64 * i];
    }
#pragma unroll
    for (int off = 32; off; off >>= 1) {
        s += __shfl_xor(s, off);
        c += __shfl_xor(c, off);
    }
    if (lane == 0)
        out[0] = (c > 0.f) ? (s / fmaxf(c, 1.f)) : 0.f;
}

extern "C" void kernel_launch(void* const* d_in, const int* in_sizes, int n_in,
                              void* d_out, int out_size, void* d_ws, size_t ws_size,
                              hipStream_t stream) {
    const float* emb    = (const float*)d_in[0];
    const int*   labels = (const int*)d_in[1];
    float*       out    = (float*)d_out;
    float*       psum   = (float*)d_ws;        // [256]
    float*       pcnt   = psum + NBLK;         // [256]

    triplet_fused_kernel<<<NBLK, NT, 0, stream>>>(emb, labels, psum, pcnt);
    finalize_kernel<<<1, 64, 0, stream>>>(psum, pcnt, out);
}